// Round 5
// baseline (41536.887 us; speedup 1.0000x reference)
//
#include <hip/hip_runtime.h>

#define SEQ  8192
#define NT   2048
#define NBLK 128
#define NTHR 1024   // 16 waves; wave wv owns row j = 16*b + wv
#define LOG2E 1.4426950408889634f
#define LN2   0.6931471805599453f

#define LOAD_AG64(p)   __hip_atomic_load((p), __ATOMIC_RELAXED, __HIP_MEMORY_SCOPE_AGENT)
#define STORE_AG(p, v) __hip_atomic_store((p), (v), __ATOMIC_RELAXED, __HIP_MEMORY_SCOPE_AGENT)

// Packed state: word i of buffer t&1 = (tag<<16) | bf16(z[i]). A single relaxed
// store publishes tag+data atomically. Consumers poll TWO adjacent words with
// one 64-bit relaxed atomic load (each dword self-tagged -> tearing harmless).
__device__ __align__(16) unsigned int g_z[2][NT];
__device__ float g_gold;

__device__ __forceinline__ unsigned int f32_to_bf16(float f) {
    unsigned int u = __float_as_uint(f);
    return (u + 0x7FFFu + ((u >> 16) & 1u)) >> 16;  // RNE
}

// ---- init: z0 = exp(tstart + feats[0]) tagged 0; other buffer invalidated ----
__global__ void crf_init(const float* __restrict__ feats,
                         const float* __restrict__ tstart) {
    int i = blockIdx.x * blockDim.x + threadIdx.x;
    if (i < NT) {
        float z0 = __builtin_exp2f((tstart[i] + feats[i]) * LOG2E);
        g_z[0][i] = f32_to_bf16(z0);   // tag 0
        g_z[1][i] = 0xFFFF0000u;       // tag never matched (t <= 8191)
    }
}

// ---- gold path score (verified in rounds 1-4) ----
__global__ void crf_gold(const float* __restrict__ feats,
                         const float* __restrict__ trans,
                         const float* __restrict__ tstart,
                         const float* __restrict__ tstop,
                         const int*   __restrict__ tags) {
    __shared__ float part[16];
    int tid = threadIdx.x;
    float acc = 0.f;
    for (int t = 1 + tid; t < SEQ; t += 1024) {
        int cur = tags[t], prev = tags[t - 1];
        acc += trans[(size_t)cur * NT + prev] + feats[(size_t)t * NT + cur];
    }
    #pragma unroll
    for (int m = 1; m < 64; m <<= 1) acc += __shfl_xor(acc, m, 64);
    if ((tid & 63) == 0) part[tid >> 6] = acc;
    __syncthreads();
    if (tid == 0) {
        float S = 0.f;
        #pragma unroll
        for (int w = 0; w < 16; ++w) S += part[w];
        int t0 = tags[0], tl = tags[SEQ - 1];
        g_gold = S + tstart[t0] + feats[t0] + tstop[tl];
    }
}

// ---- main recurrence: 128 blocks x 1024 threads ----
// Linear domain: z_t = (E z_{t-1}) * exp(feat_t) * 2^-e,  e = exponent(z[0])
// (exact power-of-2 shift, identical in every block, integer-accumulated).
// Safety: per block, ALL global polls precede the barrier and ALL stores
// follow it, so any published tag t implies that block fully read tag t-1
// => overwritten slots (t-2) are globally dead and tags are never skipped
// past a waiting reader.
__global__ void __launch_bounds__(NTHR)
crf_main(const float* __restrict__ feats, const float* __restrict__ trans,
         const float* __restrict__ tstop, float* __restrict__ out) {
    const int b   = blockIdx.x;
    const int tid = threadIdx.x;
    const int wv  = tid >> 6;
    const int l   = tid & 63;
    const int j   = b * 16 + wv;

    __shared__ float w_lds[2][NT];   // parity double-buffer
    __shared__ float s_scale[2];
    __shared__ float red[16];

    // E row in registers: E[j, l+64k] = exp(T[j, l+64k]) in [1, e)
    float E[32];
    {
        const float* trow = trans + (size_t)j * NT;
        #pragma unroll
        for (int k = 0; k < 32; ++k)
            E[k] = __builtin_exp2f(trow[l + (k << 6)] * LOG2E);
    }

    // feat exp for step 1, precomputed off the critical path
    float fexp = __builtin_exp2f(feats[(size_t)NT + j] * LOG2E);
    int esum = 0;   // only block 0 / tid 0's copy is consumed

    for (int t = 1; t < SEQ; ++t) {
        const int par = (t - 1) & 1;
        const unsigned int need = (unsigned int)(t - 1);
        unsigned long long* buf64 = (unsigned long long*)g_z[par];

        // ---- one-shot poll: 2 adjacent tagged words per thread, 1 load/retry ----
        const unsigned long long want =
            ((unsigned long long)need << 48) | ((unsigned long long)need << 16);
        unsigned long long v;
        do { v = LOAD_AG64(&buf64[tid]); }
        while ((v & 0xFFFF0000FFFF0000ull) != want);

        w_lds[par][2 * tid]     = __uint_as_float((unsigned int)(v & 0xFFFFu) << 16);
        w_lds[par][2 * tid + 1] = __uint_as_float((unsigned int)((v >> 32) & 0xFFFFu) << 16);

        if (tid == 0) {
            int e = (int)(((v >> 7) & 0xFFu)) - 127;   // exponent of bf16 word 0
            s_scale[par] = __uint_as_float((unsigned int)(127 - e) << 23);
            esum += e;
        }
        // prefetch next feat + its exp (off critical path; wave-uniform addr)
        float fexpnext = (t + 1 < SEQ)
            ? __builtin_exp2f(feats[(size_t)(t + 1) * NT + j] * LOG2E) : 0.f;
        __syncthreads();

        // ---- dot: acc = sum_k E[j, l+64k] * w[l+64k] (conflict-free LDS) ----
        float acc = 0.f;
        #pragma unroll
        for (int k = 0; k < 32; ++k)
            acc = fmaf(E[k], w_lds[par][l + (k << 6)], acc);
        #pragma unroll
        for (int m = 1; m < 64; m <<= 1) acc += __shfl_xor(acc, m, 64);

        if (l == 0) {
            float znew = acc * s_scale[par] * fexp;
            STORE_AG(&g_z[t & 1][j],
                     ((unsigned int)t << 16) | f32_to_bf16(znew));
        }
        fexp = fexpnext;
    }

    // ---- final: lse of z_{SEQ-1} with stop transitions, minus gold ----
    if (b == 0) {
        const unsigned int need = SEQ - 1;
        unsigned long long* buf64 = (unsigned long long*)g_z[(SEQ - 1) & 1];
        const unsigned long long want =
            ((unsigned long long)need << 48) | ((unsigned long long)need << 16);
        unsigned long long v;
        do { v = LOAD_AG64(&buf64[tid]); }
        while ((v & 0xFFFF0000FFFF0000ull) != want);

        float w0 = __uint_as_float((unsigned int)(v & 0xFFFFu) << 16);
        float w1 = __uint_as_float((unsigned int)((v >> 32) & 0xFFFFu) << 16);
        float acc = w0 * __builtin_exp2f(tstop[2 * tid] * LOG2E)
                  + w1 * __builtin_exp2f(tstop[2 * tid + 1] * LOG2E);
        #pragma unroll
        for (int m = 1; m < 64; m <<= 1) acc += __shfl_xor(acc, m, 64);
        if (l == 0) red[wv] = acc;
        __syncthreads();
        if (tid == 0) {
            float S = 0.f;
            #pragma unroll
            for (int w = 0; w < 16; ++w) S += red[w];
            float fwd = (__builtin_log2f(S) + (float)esum) * LN2;
            out[0] = fwd - g_gold;
        }
    }
}

extern "C" void kernel_launch(void* const* d_in, const int* in_sizes, int n_in,
                              void* d_out, int out_size, void* d_ws, size_t ws_size,
                              hipStream_t stream) {
    const float* feats  = (const float*)d_in[0];
    const float* trans  = (const float*)d_in[1];
    const float* tstart = (const float*)d_in[2];
    const float* tstop  = (const float*)d_in[3];
    const int*   tags   = (const int*)d_in[4];
    float* out = (float*)d_out;

    hipLaunchKernelGGL(crf_init, dim3(2), dim3(1024), 0, stream, feats, tstart);
    hipLaunchKernelGGL(crf_gold, dim3(1), dim3(1024), 0, stream,
                       feats, trans, tstart, tstop, tags);
    hipLaunchKernelGGL(crf_main, dim3(NBLK), dim3(NTHR), 0, stream,
                       feats, trans, tstop, out);
}

// Round 6
// 21277.072 us; speedup vs baseline: 1.9522x; 1.9522x over previous
//
#include <hip/hip_runtime.h>

#define SEQ  8192
#define NT   2048
#define NBLK 256
#define NTHR 512
#define LOG2E 1.4426950408889634f
#define LN2   0.6931471805599453f

#define STORE_AG(p, v) __hip_atomic_store((p), (v), __ATOMIC_RELAXED, __HIP_MEMORY_SCOPE_AGENT)

typedef unsigned int u32x4 __attribute__((ext_vector_type(4)));

// Device-coherent 16B load (bypasses L1/L2 -> served from LLC). Each dword
// inside is individually tagged, so 16B-level tearing is harmless.
__device__ __forceinline__ u32x4 poll_load16(const unsigned int* p) {
    u32x4 r;
    asm volatile("global_load_dwordx4 %0, %1, off sc0 sc1\n\t"
                 "s_waitcnt vmcnt(0)"
                 : "=v"(r) : "v"(p) : "memory");
    return r;
}

// Packed state: word i of buffer t&1 = (tag<<16) | bf16(z[i]). One relaxed
// dword store publishes tag+data atomically; no flags, no fences.
__device__ __align__(16) unsigned int g_z[2][NT];
__device__ float g_gold;

__device__ __forceinline__ unsigned int f32_to_bf16(float f) {
    unsigned int u = __float_as_uint(f);
    return (u + 0x7FFFu + ((u >> 16) & 1u)) >> 16;  // RNE
}

// ---- init: z0 = exp(tstart + feats[0]) tagged 0; other buffer invalidated ----
__global__ void crf_init(const float* __restrict__ feats,
                         const float* __restrict__ tstart) {
    int i = blockIdx.x * blockDim.x + threadIdx.x;
    if (i < NT) {
        float z0 = __builtin_exp2f((tstart[i] + feats[i]) * LOG2E);
        g_z[0][i] = f32_to_bf16(z0);   // tag 0
        g_z[1][i] = 0xFFFF0000u;       // tag never matched (t <= 8191)
    }
}

// ---- gold path score (verified rounds 1-5) ----
__global__ void crf_gold(const float* __restrict__ feats,
                         const float* __restrict__ trans,
                         const float* __restrict__ tstart,
                         const float* __restrict__ tstop,
                         const int*   __restrict__ tags) {
    __shared__ float part[16];
    int tid = threadIdx.x;
    float acc = 0.f;
    for (int t = 1 + tid; t < SEQ; t += 1024) {
        int cur = tags[t], prev = tags[t - 1];
        acc += trans[(size_t)cur * NT + prev] + feats[(size_t)t * NT + cur];
    }
    #pragma unroll
    for (int m = 1; m < 64; m <<= 1) acc += __shfl_xor(acc, m, 64);
    if ((tid & 63) == 0) part[tid >> 6] = acc;
    __syncthreads();
    if (tid == 0) {
        float S = 0.f;
        #pragma unroll
        for (int w = 0; w < 16; ++w) S += part[w];
        int t0 = tags[0], tl = tags[SEQ - 1];
        g_gold = S + tstart[t0] + feats[t0] + tstop[tl];
    }
}

// ---- main recurrence: 256 blocks x 512 threads (R4-proven shape) ----
// Linear domain: z_t = (E z_{t-1}) * exp(feat_t) * 2^-e, e = exponent(z[0]),
// exact power-of-2 shift, identical in every block, integer-accumulated.
// Per step: one-shot dwordx4 poll -> unpack to LDS -> barrier A -> dot ->
// wave reduce -> gather 8 packed results in LDS -> barrier B -> ONE coalesced
// 8-dword store (32B transaction) publishes the block's rows.
// Safety: all polls precede barrier A, all stores follow barrier B => tag t
// published implies t-1 fully consumed by that block => t-2 slots dead.
__global__ void __launch_bounds__(NTHR)
crf_main(const float* __restrict__ feats, const float* __restrict__ trans,
         const float* __restrict__ tstop, float* __restrict__ out) {
    const int b   = blockIdx.x;
    const int tid = threadIdx.x;
    const int wid = tid >> 6;
    const int l   = tid & 63;
    const int j   = b * 8 + wid;

    __shared__ float w_lds[2][NT];     // parity double-buffer
    __shared__ float s_scale[2];
    __shared__ unsigned int pk[8];     // packed per-wave results
    __shared__ float red[8];

    // E row in registers: E[j, l+64k] = exp(T[j, l+64k]) in [1, e)
    float E[32];
    {
        const float* trow = trans + (size_t)j * NT;
        #pragma unroll
        for (int k = 0; k < 32; ++k)
            E[k] = __builtin_exp2f(trow[l + (k << 6)] * LOG2E);
    }

    // exp(feat) for step 1, precomputed off the critical path
    float fexp = __builtin_exp2f(feats[(size_t)NT + j] * LOG2E);
    int esum = 0;   // only block 0 / tid 0's copy is consumed

    for (int t = 1; t < SEQ; ++t) {
        const int par = (t - 1) & 1;
        const unsigned int need = (unsigned int)(t - 1);
        const unsigned int* buf = g_z[par] + 4 * tid;

        // ---- one-shot poll: 4 tagged words per thread, 1 instr per retry ----
        u32x4 v;
        do { v = poll_load16(buf); }
        while ((v.x >> 16) != need || (v.y >> 16) != need ||
               (v.z >> 16) != need || (v.w >> 16) != need);

        // unpack bf16 -> f32 into LDS (contiguous 16B per thread)
        w_lds[par][4 * tid + 0] = __uint_as_float(v.x << 16);
        w_lds[par][4 * tid + 1] = __uint_as_float(v.y << 16);
        w_lds[par][4 * tid + 2] = __uint_as_float(v.z << 16);
        w_lds[par][4 * tid + 3] = __uint_as_float(v.w << 16);

        if (tid == 0) {
            int e = (int)((v.x >> 7) & 0xFFu) - 127;   // bf16 exponent of word 0
            s_scale[par] = __uint_as_float((unsigned int)(127 - e) << 23);
            esum += e;
        }
        // prefetch next feat + exp (off critical path; wave-uniform addr)
        float fexpnext = (t + 1 < SEQ)
            ? __builtin_exp2f(feats[(size_t)(t + 1) * NT + j] * LOG2E) : 0.f;
        __syncthreads();   // A: w_lds + s_scale ready

        // ---- dot: acc = sum_k E[j, l+64k] * w[l+64k] (conflict-free LDS) ----
        float acc = 0.f;
        #pragma unroll
        for (int k = 0; k < 32; ++k)
            acc = fmaf(E[k], w_lds[par][l + (k << 6)], acc);
        #pragma unroll
        for (int m = 1; m < 64; m <<= 1) acc += __shfl_xor(acc, m, 64);

        if (l == 0) {
            float znew = acc * s_scale[par] * fexp;
            pk[wid] = ((unsigned int)t << 16) | f32_to_bf16(znew);
        }
        fexp = fexpnext;
        __syncthreads();   // B: all 8 results gathered

        // ---- ONE coalesced publication: lanes 0-7, 8 contiguous dwords ----
        if (tid < 8) STORE_AG(&g_z[t & 1][b * 8 + tid], pk[tid]);
    }

    // ---- final: lse of z_{SEQ-1} with stop transitions, minus gold ----
    if (b == 0) {
        const unsigned int need = SEQ - 1;
        const unsigned int* buf = g_z[(SEQ - 1) & 1] + 4 * tid;
        u32x4 v;
        do { v = poll_load16(buf); }
        while ((v.x >> 16) != need || (v.y >> 16) != need ||
               (v.z >> 16) != need || (v.w >> 16) != need);

        float acc =
            __uint_as_float(v.x << 16) * __builtin_exp2f(tstop[4 * tid + 0] * LOG2E) +
            __uint_as_float(v.y << 16) * __builtin_exp2f(tstop[4 * tid + 1] * LOG2E) +
            __uint_as_float(v.z << 16) * __builtin_exp2f(tstop[4 * tid + 2] * LOG2E) +
            __uint_as_float(v.w << 16) * __builtin_exp2f(tstop[4 * tid + 3] * LOG2E);
        #pragma unroll
        for (int m = 1; m < 64; m <<= 1) acc += __shfl_xor(acc, m, 64);
        if (l == 0) red[wid] = acc;
        __syncthreads();
        if (tid == 0) {
            float S = 0.f;
            #pragma unroll
            for (int w = 0; w < 8; ++w) S += red[w];
            float fwd = (__builtin_log2f(S) + (float)esum) * LN2;
            out[0] = fwd - g_gold;
        }
    }
}

extern "C" void kernel_launch(void* const* d_in, const int* in_sizes, int n_in,
                              void* d_out, int out_size, void* d_ws, size_t ws_size,
                              hipStream_t stream) {
    const float* feats  = (const float*)d_in[0];
    const float* trans  = (const float*)d_in[1];
    const float* tstart = (const float*)d_in[2];
    const float* tstop  = (const float*)d_in[3];
    const int*   tags   = (const int*)d_in[4];
    float* out = (float*)d_out;

    hipLaunchKernelGGL(crf_init, dim3(2), dim3(1024), 0, stream, feats, tstart);
    hipLaunchKernelGGL(crf_gold, dim3(1), dim3(1024), 0, stream,
                       feats, trans, tstart, tstop, tags);
    hipLaunchKernelGGL(crf_main, dim3(NBLK), dim3(NTHR), 0, stream,
                       feats, trans, tstop, out);
}